// Round 4
// baseline (386.802 us; speedup 1.0000x reference)
//
#include <hip/hip_runtime.h>

// B=64, H=W=32, HW=1024, steps=256, backtrack 255.
// Outputs: [histories 65536][paths 65536][pred_cost 65536] float32.
// Single fused kernel: 64 blocks (1 per batch) x 256 threads.
//   Phase 1 (all 256 thr): conv1(2->32)+ReLU, conv2(32->1)+sigmoid — bit-exact
//            op order vs the round-1 kernels (absmax 0.0). Unchanged.
//   Phase 2 (wave 0 only, no barriers): 256 A* steps with the argmax keys in
//            REGISTERS (hi[16] per lane; cell = j*64+lane). All cell-state
//            mutations happen on the owner lane (relax lane == owner lane by
//            the parity mapping), so keys/open/hist/obs live in lane registers;
//            only {g,hpc} (candidate reads), cost (uniform read) and parents
//            stay in LDS. One LDS latency window per step (sel + 2 candidates
//            issued together). Register updates via 16-way cndmask loop
//            (jsel/jB scalar, vjA per-half).
//   Phase 3 (all): backtrack (lane 0) + output writes (hist bits via LDS dump).

#define HW 1024

// DPP wave-64 max-reduce step on a u64 key (hi=value bits, lo=1023-cell).
// row_shr accumulates into lanes 15/31/47/63; bcast15/31 -> lane 63 holds max.
#define DPP_MAX64(key, ctrl) do {                                              \
    unsigned int _lo = (unsigned int)(key);                                    \
    unsigned int _hi = (unsigned int)((key) >> 32);                            \
    unsigned int _slo = (unsigned int)__builtin_amdgcn_update_dpp(             \
        (int)_lo, (int)_lo, (ctrl), 0xf, 0xf, false);                          \
    unsigned int _shi = (unsigned int)__builtin_amdgcn_update_dpp(             \
        (int)_hi, (int)_hi, (ctrl), 0xf, 0xf, false);                          \
    unsigned long long _o = ((unsigned long long)_shi << 32) | _slo;           \
    if (_o > (key)) (key) = _o;                                                \
} while (0)

__global__ __launch_bounds__(256) void fused_nastar(
    const float* __restrict__ maps, const float* __restrict__ start,
    const float* __restrict__ goal, const float* __restrict__ w1,
    const float* __restrict__ b1, const float* __restrict__ w2,
    const float* __restrict__ b2, float* __restrict__ out_hist,
    float* __restrict__ out_path, float* __restrict__ out_cost) {
  __shared__ float hid[8][HW];            // 32 KB
  __shared__ float cost_sh[HW];           // 4 KB
  __shared__ float2 gh[HW];               // 8 KB: {g, heuristic+cost}
  __shared__ unsigned short par[HW];      // 2 KB
  __shared__ unsigned char path_sh[HW];   // 1 KB
  __shared__ unsigned int hist_lds[64];   // 256 B
  // total ~47.3 KB

  const int t = threadIdx.x;
  const int b = blockIdx.x;
  const float C_INV = 0.17677669529663687f;  // float32(1/sqrt(32))

  const float* m_p = maps  + b * HW;
  const float* s_p = start + b * HW;
  const float* g_p = goal  + b * HW;

  // ---------------- Phase 1: encoder (unchanged, bit-exact) ----------------
  const int base = t * 4;
  float acc2[4] = {b2[0], b2[0], b2[0], b2[0]};
  for (int grp = 0; grp < 4; ++grp) {
    #pragma unroll
    for (int p = 0; p < 4; ++p) {
      int pix = base + p;
      int y = pix >> 5, x = pix & 31;
      float win0[9], win1[9];
      #pragma unroll
      for (int ky = 0; ky < 3; ++ky) {
        #pragma unroll
        for (int kx = 0; kx < 3; ++kx) {
          int yy = y + ky - 1, xx = x + kx - 1;
          bool ok = (yy >= 0) && (yy <= 31) && (xx >= 0) && (xx <= 31);
          int q = ok ? yy * 32 + xx : 0;
          float v0 = m_p[q];
          float v1 = s_p[q] + g_p[q];
          win0[ky * 3 + kx] = ok ? v0 : 0.0f;
          win1[ky * 3 + kx] = ok ? v1 : 0.0f;
        }
      }
      #pragma unroll
      for (int ocl = 0; ocl < 8; ++ocl) {
        int oc = grp * 8 + ocl;
        const float* w = w1 + oc * 18;
        float acc = b1[oc];
        #pragma unroll
        for (int k = 0; k < 9; ++k) {
          acc += win0[k] * w[k];
          acc += win1[k] * w[9 + k];
        }
        hid[ocl][pix] = fmaxf(acc, 0.0f);
      }
    }
    __syncthreads();
    #pragma unroll
    for (int p = 0; p < 4; ++p) {
      int pix = base + p;
      int y = pix >> 5, x = pix & 31;
      float a = acc2[p];
      #pragma unroll
      for (int ocl = 0; ocl < 8; ++ocl) {
        int ic = grp * 8 + ocl;
        const float* w = w2 + ic * 9;
        #pragma unroll
        for (int ky = 0; ky < 3; ++ky) {
          #pragma unroll
          for (int kx = 0; kx < 3; ++kx) {
            int yy = y + ky - 1, xx = x + kx - 1;
            bool ok = (yy >= 0) && (yy <= 31) && (xx >= 0) && (xx <= 31);
            int q = ok ? yy * 32 + xx : 0;
            float hv = hid[ocl][q];
            a += (ok ? hv : 0.0f) * w[ky * 3 + kx];
          }
        }
      }
      acc2[p] = a;
    }
    __syncthreads();
  }
  float cost4[4];
  #pragma unroll
  for (int p = 0; p < 4; ++p) {
    cost4[p] = 1.0f / (1.0f + expf(-acc2[p]));
    cost_sh[base + p] = cost4[p];
  }
  *reinterpret_cast<float4*>(out_cost + b * HW + base) =
      make_float4(cost4[0], cost4[1], cost4[2], cost4[3]);
  __syncthreads();

  // ---------------- Phase 2: A* (wave 0, register-resident keys) -----------
  if (t < 64) {
    const int lane = t;
    reinterpret_cast<int4*>(path_sh)[lane] = make_int4(0, 0, 0, 0);
    // goal via ballot (one-hot)
    int myg = -1;
    #pragma unroll
    for (int j = 0; j < 16; ++j) {
      int cell = j * 64 + lane;
      if (g_p[cell] > 0.5f) myg = cell;
    }
    unsigned long long gm = __ballot(myg >= 0);
    int src_lane = (int)__ffsll(gm) - 1;
    const int goal_idx = __shfl(myg, src_lane, 64);
    const int gy = goal_idx >> 5, gx = goal_idx & 31;

    // per-lane state: hi[16] key value-bits, 16-bit masks
    unsigned int hi[16];
    unsigned int open_m = 0, hist_m = 0, obs_m = 0;
    #pragma unroll
    for (int j = 0; j < 16; ++j) {
      int cell = j * 64 + lane;
      int y = cell >> 5, x = cell & 31;
      float cst = cost_sh[cell];
      int dy = y - gy; dy = dy < 0 ? -dy : dy;
      int dx = x - gx; dx = dx < 0 ? -dx : dx;
      float e = sqrtf((float)(dy * dy + dx * dx));
      float heur = __fadd_rn((float)(dy + dx), __fmul_rn(0.001f, e));
      float hc = __fadd_rn(heur, cst);       // h4 = heuristic + cost
      gh[cell] = make_float2(0.0f, hc);
      bool isobs = (m_p[cell] != 0.0f);
      bool isst  = (s_p[cell] > 0.5f);
      if (isobs) obs_m  |= 1u << j;
      if (isst)  open_m |= 1u << j;
      float f = 0.5f * (0.0f + hc);
      float ex = expf(__fmul_rn(-f, C_INV));
      hi[j] = isst ? __float_as_uint(ex) : 0u;
      par[cell] = (unsigned short)goal_idx;
    }

    const int x = lane & 31, half = lane >> 5;
    const unsigned int lowbase = 1023u - (unsigned)lane;  // lo = lowbase - 64j

    for (int step = 0; step < 256; ++step) {
      // local 16->1 max tree on u64 keys (registers only)
      unsigned long long k[16];
      #pragma unroll
      for (int j = 0; j < 16; ++j)
        k[j] = ((unsigned long long)hi[j] << 32) | (lowbase - 64u * (unsigned)j);
      #pragma unroll
      for (int s = 8; s >= 1; s >>= 1) {
        #pragma unroll
        for (int i = 0; i < s; ++i)
          if (k[i + s] > k[i]) k[i] = k[i + s];
      }
      unsigned long long key = k[0];
      DPP_MAX64(key, 0x111);  // row_shr:1
      DPP_MAX64(key, 0x112);  // row_shr:2
      DPP_MAX64(key, 0x114);  // row_shr:4
      DPP_MAX64(key, 0x118);  // row_shr:8
      DPP_MAX64(key, 0x142);  // row_bcast:15
      DPP_MAX64(key, 0x143);  // row_bcast:31
      unsigned int klo =
          (unsigned int)__builtin_amdgcn_readlane((int)(unsigned int)key, 63);
      const int sel = __builtin_amdgcn_readfirstlane(1023 - (int)klo);
      const int jsel = sel >> 6, owner = sel & 63;
      const int ys = sel >> 5, xs = sel & 31;
      const bool unsolved = (sel != goal_idx);

      // candidate geometry (relax lane == owner lane of its target cells)
      int dxs = x - xs; int adx = dxs < 0 ? -dxs : dxs;
      const bool act = (adx <= 1);
      const bool samep = (((ys ^ half) & 1) == 0);
      const int yA = samep ? ys : (ys - 1);
      const bool vAv = act && (samep ? (adx >= 1) : (yA >= 0));
      const int yB = ys + 1;
      const bool vBv = act && (!samep) && (yB <= 31);
      const int cA = vAv ? (yA * 32 + x) : 0;
      const int cB = vBv ? (yB * 32 + x) : 0;

      // one LDS latency window: uniform sel reads + per-lane candidate reads
      float2 ghs = gh[sel];
      float  css = cost_sh[sel];
      float2 rA  = gh[cA];
      float2 rB  = gh[cB];

      const float gsum = ghs.x + css;        // g2 value (exact, as reference)
      const int vjA = yA >> 1;               // per-half index (VGPR)
      const int jB  = yB >> 1;               // scalar

      bool obA = (obs_m  >> (vjA & 15)) & 1;
      bool opA = (open_m >> (vjA & 15)) & 1;
      bool hiA = (hist_m >> (vjA & 15)) & 1;
      bool obB = (obs_m  >> (jB  & 15)) & 1;
      bool opB = (open_m >> (jB  & 15)) & 1;
      bool hiB = (hist_m >> (jB  & 15)) & 1;

      const bool idxA = vAv && obA && ((!opA && !hiA) || (opA && (rA.x > gsum)));
      const bool idxB = vBv && obB && ((!opB && !hiB) || (opB && (rB.x > gsum)));
      const bool closeU = unsolved && (lane == owner);

      float fA = 0.5f * (gsum + rA.y);
      unsigned int nvA = __float_as_uint(expf(__fmul_rn(-fA, C_INV)));
      float fB = 0.5f * (gsum + rB.y);
      unsigned int nvB = __float_as_uint(expf(__fmul_rn(-fB, C_INV)));

      // register key updates (close + A + B target disjoint (lane,j) slots)
      #pragma unroll
      for (int j = 0; j < 16; ++j) {
        unsigned int h = hi[j];
        h = (closeU && (j == jsel)) ? 0u  : h;
        h = (idxA  && (j == vjA))  ? nvA : h;
        h = (idxB  && (j == jB))   ? nvB : h;
        hi[j] = h;
      }
      hist_m |= (lane == owner) ? (1u << jsel) : 0u;
      unsigned int clr = closeU ? (1u << jsel) : 0u;
      unsigned int aA  = idxA ? (1u << (vjA & 15)) : 0u;
      unsigned int aB  = idxB ? (1u << (jB  & 15)) : 0u;
      open_m = (open_m & ~clr) | aA | aB;

      if (idxA) { gh[cA].x = gsum; par[cA] = (unsigned short)sel; }
      if (idxB) { gh[cB].x = gsum; par[cB] = (unsigned short)sel; }
    }

    hist_lds[lane] = hist_m;

    // backtrack (parent table static; revisit => cycle => exact early exit)
    if (lane == 0) {
      path_sh[goal_idx] = 1;
      int loc = par[goal_idx];
      for (int i = 0; i < 255; ++i) {
        if (path_sh[loc]) break;
        path_sh[loc] = 1;
        loc = par[loc];
      }
    }
  }
  __syncthreads();

  // ---------------- Phase 3: outputs ----------------
  float hv[4], pv[4];
  #pragma unroll
  for (int p = 0; p < 4; ++p) {
    int cell = base + p;
    hv[p] = (float)((hist_lds[cell & 63] >> (cell >> 6)) & 1);
    pv[p] = (float)path_sh[cell];
  }
  *reinterpret_cast<float4*>(out_hist + b * HW + base) =
      make_float4(hv[0], hv[1], hv[2], hv[3]);
  *reinterpret_cast<float4*>(out_path + b * HW + base) =
      make_float4(pv[0], pv[1], pv[2], pv[3]);
}

extern "C" void kernel_launch(void* const* d_in, const int* in_sizes, int n_in,
                              void* d_out, int out_size, void* d_ws, size_t ws_size,
                              hipStream_t stream) {
  (void)in_sizes; (void)n_in; (void)d_ws; (void)ws_size; (void)out_size;
  const float* maps  = (const float*)d_in[0];
  const float* start = (const float*)d_in[1];
  const float* goal  = (const float*)d_in[2];
  const float* w1    = (const float*)d_in[3];
  const float* b1    = (const float*)d_in[4];
  const float* w2    = (const float*)d_in[5];
  const float* b2    = (const float*)d_in[6];

  float* out      = (float*)d_out;
  float* out_hist = out;
  float* out_path = out + 64 * HW;
  float* out_cost = out + 128 * HW;

  fused_nastar<<<64, 256, 0, stream>>>(maps, start, goal, w1, b1, w2, b2,
                                       out_hist, out_path, out_cost);
}

// Round 5
// 135.682 us; speedup vs baseline: 2.8508x; 2.8508x over previous
//
#include <hip/hip_runtime.h>

// B=64, H=W=32, HW=1024, steps<=256, backtrack 255.
// Outputs: [histories 65536][paths 65536][pred_cost 65536] float32.
// Single fused kernel: 64 blocks (1 per batch) x 256 threads.
//   Phase 1 (all 256 thr): conv1(2->32)+ReLU, conv2(32->1)+sigmoid.
//            Pixel mapping pix = p*256 + t -> lane-contiguous LDS access
//            (round-3/4 mapping pix=4t+p caused ~865k 8-way bank conflicts).
//            Per-pixel accumulation order is bit-identical to round 1 (absmax 0).
//   Phase 2 (wave 0 only, no barriers): A* steps with LDS vkey scan (stride-64
//            words = 2-way = free), register obs/open/hist masks (round-4
//            proven), separate f32 LDS arrays g_l/h_l/c_l (stride-1 candidate
//            reads + uniform sel reads, one latency window per step).
//            FREEZE BREAK: if a step changes nothing (ballot==0), the state is
//            a fixed point -> all remaining steps are no-ops -> exact break.
//   Phase 3 (all): backtrack (lane 0) + output writes.

#define HW 1024

// DPP wave-64 max-reduce step on a u64 key (hi=value bits, lo=1023-cell).
// row_shr accumulates into lanes 15/31/47/63; bcast15/31 -> lane 63 holds max.
#define DPP_MAX64(key, ctrl) do {                                              \
    unsigned int _lo = (unsigned int)(key);                                    \
    unsigned int _hi = (unsigned int)((key) >> 32);                            \
    unsigned int _slo = (unsigned int)__builtin_amdgcn_update_dpp(             \
        (int)_lo, (int)_lo, (ctrl), 0xf, 0xf, false);                          \
    unsigned int _shi = (unsigned int)__builtin_amdgcn_update_dpp(             \
        (int)_hi, (int)_hi, (ctrl), 0xf, 0xf, false);                          \
    unsigned long long _o = ((unsigned long long)_shi << 32) | _slo;           \
    if (_o > (key)) (key) = _o;                                                \
} while (0)

__global__ __launch_bounds__(256) void fused_nastar(
    const float* __restrict__ maps, const float* __restrict__ start,
    const float* __restrict__ goal, const float* __restrict__ w1,
    const float* __restrict__ b1, const float* __restrict__ w2,
    const float* __restrict__ b2, float* __restrict__ out_hist,
    float* __restrict__ out_path, float* __restrict__ out_cost) {
  __shared__ float hid[8][HW];            // 32 KB
  __shared__ float c_l[HW];               // 4 KB: cost
  __shared__ float g_l[HW];               // 4 KB: g
  __shared__ float h_l[HW];               // 4 KB: heuristic + cost (h4)
  __shared__ unsigned int vkey[HW];       // 4 KB: f32 bits of v (0 if closed)
  __shared__ unsigned short par[HW];      // 2 KB
  __shared__ unsigned char path_sh[HW];   // 1 KB
  __shared__ unsigned int hist_lds[64];   // 256 B
  // ~51.3 KB

  const int t = threadIdx.x;
  const int b = blockIdx.x;
  const float C_INV = 0.17677669529663687f;  // float32(1/sqrt(32))

  const float* m_p = maps  + b * HW;
  const float* s_p = start + b * HW;
  const float* g_p = goal  + b * HW;

  // ---------------- Phase 1: encoder (lane-contiguous pixel map) -----------
  float acc2[4] = {b2[0], b2[0], b2[0], b2[0]};
  for (int grp = 0; grp < 4; ++grp) {
    #pragma unroll
    for (int p = 0; p < 4; ++p) {
      int pix = p * 256 + t;
      int y = pix >> 5, x = pix & 31;
      float win0[9], win1[9];
      #pragma unroll
      for (int ky = 0; ky < 3; ++ky) {
        #pragma unroll
        for (int kx = 0; kx < 3; ++kx) {
          int yy = y + ky - 1, xx = x + kx - 1;
          bool ok = (yy >= 0) && (yy <= 31) && (xx >= 0) && (xx <= 31);
          int q = ok ? yy * 32 + xx : 0;
          float v0 = m_p[q];
          float v1 = s_p[q] + g_p[q];
          win0[ky * 3 + kx] = ok ? v0 : 0.0f;
          win1[ky * 3 + kx] = ok ? v1 : 0.0f;
        }
      }
      #pragma unroll
      for (int ocl = 0; ocl < 8; ++ocl) {
        int oc = grp * 8 + ocl;
        const float* w = w1 + oc * 18;
        float acc = b1[oc];
        #pragma unroll
        for (int k = 0; k < 9; ++k) {
          acc += win0[k] * w[k];       // same per-pixel op order as round 1
          acc += win1[k] * w[9 + k];
        }
        hid[ocl][pix] = fmaxf(acc, 0.0f);
      }
    }
    __syncthreads();
    #pragma unroll
    for (int p = 0; p < 4; ++p) {
      int pix = p * 256 + t;
      int y = pix >> 5, x = pix & 31;
      float a = acc2[p];
      #pragma unroll
      for (int ocl = 0; ocl < 8; ++ocl) {
        int ic = grp * 8 + ocl;
        const float* w = w2 + ic * 9;
        #pragma unroll
        for (int ky = 0; ky < 3; ++ky) {
          #pragma unroll
          for (int kx = 0; kx < 3; ++kx) {
            int yy = y + ky - 1, xx = x + kx - 1;
            bool ok = (yy >= 0) && (yy <= 31) && (xx >= 0) && (xx <= 31);
            int q = ok ? yy * 32 + xx : 0;
            float hv = hid[ocl][q];
            a += (ok ? hv : 0.0f) * w[ky * 3 + kx];
          }
        }
      }
      acc2[p] = a;
    }
    __syncthreads();
  }
  #pragma unroll
  for (int p = 0; p < 4; ++p) {
    int pix = p * 256 + t;
    float c = 1.0f / (1.0f + expf(-acc2[p]));
    c_l[pix] = c;
    out_cost[b * HW + pix] = c;          // stride-1 across lanes: coalesced
  }
  __syncthreads();

  // ---------------- Phase 2: A* (wave 0, LDS scan + register masks) --------
  if (t < 64) {
    const int lane = t;
    reinterpret_cast<int4*>(path_sh)[lane] = make_int4(0, 0, 0, 0);
    // goal via ballot (one-hot)
    int myg = -1;
    #pragma unroll
    for (int j = 0; j < 16; ++j) {
      int cell = j * 64 + lane;
      if (g_p[cell] > 0.5f) myg = cell;
    }
    unsigned long long gm = __ballot(myg >= 0);
    int src_lane = (int)__ffsll(gm) - 1;
    const int goal_idx = __shfl(myg, src_lane, 64);
    const int gy = goal_idx >> 5, gx = goal_idx & 31;

    unsigned int open_m = 0, hist_m = 0, obs_m = 0;
    #pragma unroll
    for (int j = 0; j < 16; ++j) {
      int cell = j * 64 + lane;
      int y = cell >> 5, x = cell & 31;
      float cst = c_l[cell];
      int dy = y - gy; dy = dy < 0 ? -dy : dy;
      int dx = x - gx; dx = dx < 0 ? -dx : dx;
      float e = sqrtf((float)(dy * dy + dx * dx));
      float heur = __fadd_rn((float)(dy + dx), __fmul_rn(0.001f, e));
      float hc = __fadd_rn(heur, cst);       // h4 = heuristic + cost
      h_l[cell] = hc;
      g_l[cell] = 0.0f;
      bool isobs = (m_p[cell] != 0.0f);
      bool isst  = (s_p[cell] > 0.5f);
      if (isobs) obs_m  |= 1u << j;
      if (isst)  open_m |= 1u << j;
      float f = 0.5f * (0.0f + hc);
      float ex = expf(__fmul_rn(-f, C_INV));
      vkey[cell] = isst ? __float_as_uint(ex) : 0u;
      par[cell] = (unsigned short)goal_idx;
    }

    const int x = lane & 31, half = lane >> 5;
    const unsigned int lowbase = 1023u - (unsigned)lane;  // lo = lowbase - 64j

    for (int step = 0; step < 256; ++step) {
      // LDS scan (stride-64 words = conflict-free) + local 16->1 max tree
      unsigned long long k[16];
      #pragma unroll
      for (int j = 0; j < 16; ++j) {
        unsigned int v = vkey[j * 64 + lane];
        k[j] = ((unsigned long long)v << 32) | (lowbase - 64u * (unsigned)j);
      }
      #pragma unroll
      for (int s = 8; s >= 1; s >>= 1) {
        #pragma unroll
        for (int i = 0; i < s; ++i)
          if (k[i + s] > k[i]) k[i] = k[i + s];
      }
      unsigned long long key = k[0];
      DPP_MAX64(key, 0x111);  // row_shr:1
      DPP_MAX64(key, 0x112);  // row_shr:2
      DPP_MAX64(key, 0x114);  // row_shr:4
      DPP_MAX64(key, 0x118);  // row_shr:8
      DPP_MAX64(key, 0x142);  // row_bcast:15
      DPP_MAX64(key, 0x143);  // row_bcast:31
      unsigned int klo =
          (unsigned int)__builtin_amdgcn_readlane((int)(unsigned int)key, 63);
      const int sel = __builtin_amdgcn_readfirstlane(1023 - (int)klo);
      const int jsel = sel >> 6, owner = sel & 63;
      const int ys = sel >> 5, xs = sel & 31;
      const bool unsolved = (sel != goal_idx);

      // candidate geometry (relax lane == owner lane; round-4 proven)
      int dxs = x - xs; int adx = dxs < 0 ? -dxs : dxs;
      const bool act = (adx <= 1);
      const bool samep = (((ys ^ half) & 1) == 0);
      const int yA = samep ? ys : (ys - 1);
      const bool vAv = act && (samep ? (adx >= 1) : (yA >= 0));
      const int yB = ys + 1;
      const bool vBv = act && (!samep) && (yB <= 31);
      const int cA = vAv ? (yA * 32 + x) : 0;
      const int cB = vBv ? (yB * 32 + x) : 0;

      // one LDS latency window: uniform sel reads + stride-1 candidate reads
      float gs = g_l[sel];
      float cs = c_l[sel];
      float gA = g_l[cA], hA = h_l[cA];
      float gB = g_l[cB], hB = h_l[cB];

      const float gsum = gs + cs;            // g2 value (exact, as reference)
      const int vjA = yA >> 1;               // candidate j (per-half value)
      const int jB  = yB >> 1;

      bool obA = (obs_m  >> (vjA & 15)) & 1;
      bool opA = (open_m >> (vjA & 15)) & 1;
      bool hiA = (hist_m >> (vjA & 15)) & 1;
      bool obB = (obs_m  >> (jB  & 15)) & 1;
      bool opB = (open_m >> (jB  & 15)) & 1;
      bool hiB = (hist_m >> (jB  & 15)) & 1;

      const bool idxA = vAv && obA && ((!opA && !hiA) || (opA && (gA > gsum)));
      const bool idxB = vBv && obB && ((!opB && !hiB) || (opB && (gB > gsum)));
      const bool ownerlane = (lane == owner);
      const bool closeU = unsolved && ownerlane;

      // change detection (pre-update bits)
      const bool histnew = ownerlane && !((hist_m >> (jsel & 15)) & 1);
      const bool opencl  = closeU && ((open_m >> (jsel & 15)) & 1);

      // mask updates
      hist_m |= ownerlane ? (1u << (jsel & 15)) : 0u;
      unsigned int clr = closeU ? (1u << (jsel & 15)) : 0u;
      unsigned int aA  = idxA ? (1u << (vjA & 15)) : 0u;
      unsigned int aB  = idxB ? (1u << (jB  & 15)) : 0u;
      open_m = (open_m & ~clr) | aA | aB;

      // LDS updates (exec-masked)
      if (closeU) vkey[sel] = 0u;
      float fA = 0.5f * (gsum + hA);
      unsigned int nvA = __float_as_uint(expf(__fmul_rn(-fA, C_INV)));
      float fB = 0.5f * (gsum + hB);
      unsigned int nvB = __float_as_uint(expf(__fmul_rn(-fB, C_INV)));
      if (idxA) { g_l[cA] = gsum; vkey[cA] = nvA; par[cA] = (unsigned short)sel; }
      if (idxB) { g_l[cB] = gsum; vkey[cB] = nvB; par[cB] = (unsigned short)sel; }

      // freeze: nothing changed => fixed point => all remaining steps no-ops
      unsigned long long anych = __ballot(idxA || idxB || histnew || opencl);
      if (anych == 0ull) break;
    }

    hist_lds[lane] = hist_m;

    // backtrack (parent table static; revisit => cycle => exact early exit)
    if (lane == 0) {
      path_sh[goal_idx] = 1;
      int loc = par[goal_idx];
      for (int i = 0; i < 255; ++i) {
        if (path_sh[loc]) break;
        path_sh[loc] = 1;
        loc = par[loc];
      }
    }
  }
  __syncthreads();

  // ---------------- Phase 3: outputs ----------------
  const int base = t * 4;
  float hv[4], pv[4];
  #pragma unroll
  for (int p = 0; p < 4; ++p) {
    int cell = base + p;
    hv[p] = (float)((hist_lds[cell & 63] >> (cell >> 6)) & 1);
    pv[p] = (float)path_sh[cell];
  }
  *reinterpret_cast<float4*>(out_hist + b * HW + base) =
      make_float4(hv[0], hv[1], hv[2], hv[3]);
  *reinterpret_cast<float4*>(out_path + b * HW + base) =
      make_float4(pv[0], pv[1], pv[2], pv[3]);
}

extern "C" void kernel_launch(void* const* d_in, const int* in_sizes, int n_in,
                              void* d_out, int out_size, void* d_ws, size_t ws_size,
                              hipStream_t stream) {
  (void)in_sizes; (void)n_in; (void)d_ws; (void)ws_size; (void)out_size;
  const float* maps  = (const float*)d_in[0];
  const float* start = (const float*)d_in[1];
  const float* goal  = (const float*)d_in[2];
  const float* w1    = (const float*)d_in[3];
  const float* b1    = (const float*)d_in[4];
  const float* w2    = (const float*)d_in[5];
  const float* b2    = (const float*)d_in[6];

  float* out      = (float*)d_out;
  float* out_hist = out;
  float* out_path = out + 64 * HW;
  float* out_cost = out + 128 * HW;

  fused_nastar<<<64, 256, 0, stream>>>(maps, start, goal, w1, b1, w2, b2,
                                       out_hist, out_path, out_cost);
}